// Round 3
// baseline (76.897 us; speedup 1.0000x reference)
//
#include <hip/hip_runtime.h>
#include <math.h>

// Chamfer distance: B=16, N=M=2048, D=3, fp32.
// Stage 1 (1024 blocks, 4/CU): per (dir,batch,slice) block computes partial
//   minima of s_j = |y_j|^2 - 2 x.y_j over a 64-point opposing slice for all
//   2048 source points (8/thread -> 32 VALU per ds_read_b128).
//   Block 0 also zeroes the stage-2 ticket counter in d_ws.
// Stage 2 (256 blocks): min over 32 slices, add |x|^2, block-sum; last block
//   (ticket pattern, device-scope atomics) sums the 256 block sums -> out[0].

#define BATCH   16
#define NPTS    2048
#define KSLICE  32
#define SLICE   64           // NPTS / KSLICE
#define SPT     8            // src points per thread (stage 1)
#define NCOMBO  32           // 2 dirs x 16 batches
#define NBLK2   256          // stage-2 grid

__global__ __launch_bounds__(256) void chamfer_partial(
    const float* __restrict__ preds,
    const float* __restrict__ tgts,
    float* __restrict__ partial,
    int* __restrict__ counter)
{
    __shared__ float4 q[SLICE];   // 1 KB

    const int bid   = blockIdx.x;     // 0..1023
    const int combo = bid & (NCOMBO - 1);
    const int slice = bid >> 5;       // 0..31
    const int dir   = combo >> 4;
    const int b     = combo & 15;

    if (bid == 0 && threadIdx.x == 0) *counter = 0;

    const float* src = (dir ? tgts : preds) + (size_t)b * NPTS * 3;
    const float* opp = (dir ? preds : tgts) + (size_t)b * NPTS * 3;

    if (threadIdx.x < SLICE) {
        const int jj = slice * SLICE + threadIdx.x;
        const float y0 = opp[3 * jj + 0];
        const float y1 = opp[3 * jj + 1];
        const float y2 = opp[3 * jj + 2];
        q[threadIdx.x] = make_float4(y0, y1, y2, y0 * y0 + y1 * y1 + y2 * y2);
    }

    float n0[SPT], n1[SPT], n2[SPT], m[SPT];
    #pragma unroll
    for (int k = 0; k < SPT; k++) {
        const int i = threadIdx.x + 256 * k;
        n0[k] = -2.0f * src[3 * i + 0];
        n1[k] = -2.0f * src[3 * i + 1];
        n2[k] = -2.0f * src[3 * i + 2];
        m[k]  = INFINITY;
    }
    __syncthreads();

    #pragma unroll 2
    for (int j = 0; j < SLICE; j++) {
        const float4 Q = q[j];
        #pragma unroll
        for (int k = 0; k < SPT; k++) {
            const float s = fmaf(n0[k], Q.x, fmaf(n1[k], Q.y, fmaf(n2[k], Q.z, Q.w)));
            m[k] = fminf(m[k], s);
        }
    }

    float* pp = partial + ((size_t)combo * KSLICE + slice) * NPTS;
    #pragma unroll
    for (int k = 0; k < SPT; k++)
        pp[threadIdx.x + 256 * k] = m[k];
}

__global__ __launch_bounds__(256) void chamfer_reduce(
    const float* __restrict__ preds,
    const float* __restrict__ tgts,
    const float* __restrict__ partial,
    float* __restrict__ blocksum,
    int* __restrict__ counter,
    float* __restrict__ out)
{
    __shared__ float wsum[4];
    __shared__ bool  amLast;

    const int idx   = blockIdx.x * 256 + threadIdx.x;   // 0..65535
    const int combo = idx >> 11;                        // uniform per block
    const int i     = idx & (NPTS - 1);
    const int dir   = combo >> 4;
    const int b     = combo & 15;

    const float* src = (dir ? tgts : preds) + (size_t)b * NPTS * 3;
    const float x0 = src[3 * i + 0];
    const float x1 = src[3 * i + 1];
    const float x2 = src[3 * i + 2];
    const float xx = x0 * x0 + x1 * x1 + x2 * x2;

    const float* pp = partial + (size_t)combo * KSLICE * NPTS + i;
    float mn = pp[0];
    #pragma unroll
    for (int s = 1; s < KSLICE; s++)
        mn = fminf(mn, pp[(size_t)s * NPTS]);

    float val = xx + mn;

    #pragma unroll
    for (int off = 32; off > 0; off >>= 1)
        val += __shfl_down(val, off, 64);

    const int lane = threadIdx.x & 63;
    const int wid  = threadIdx.x >> 6;
    if (lane == 0) wsum[wid] = val;
    __syncthreads();

    if (threadIdx.x == 0) {
        const float bsum = wsum[0] + wsum[1] + wsum[2] + wsum[3];
        __hip_atomic_store(&blocksum[blockIdx.x], bsum,
                           __ATOMIC_RELAXED, __HIP_MEMORY_SCOPE_AGENT);
        __threadfence();
        amLast = (atomicAdd(counter, 1) == NBLK2 - 1);
    }
    __syncthreads();

    if (amLast) {
        __threadfence();
        float v = __hip_atomic_load(&blocksum[threadIdx.x],
                                    __ATOMIC_RELAXED, __HIP_MEMORY_SCOPE_AGENT);
        #pragma unroll
        for (int off = 32; off > 0; off >>= 1)
            v += __shfl_down(v, off, 64);
        if (lane == 0) wsum[wid] = v;
        __syncthreads();
        if (threadIdx.x == 0)
            out[0] = wsum[0] + wsum[1] + wsum[2] + wsum[3];
    }
}

extern "C" void kernel_launch(void* const* d_in, const int* in_sizes, int n_in,
                              void* d_out, int out_size, void* d_ws, size_t ws_size,
                              hipStream_t stream) {
    const float* preds = (const float*)d_in[0];
    const float* tgts  = (const float*)d_in[1];
    float* out      = (float*)d_out;
    float* partial  = (float*)d_ws;                       // 32*32*2048 floats = 8 MB
    float* blocksum = partial + (size_t)NCOMBO * KSLICE * NPTS;  // 256 floats
    int*   counter  = (int*)(blocksum + NBLK2);

    chamfer_partial<<<NCOMBO * KSLICE, 256, 0, stream>>>(preds, tgts, partial, counter);
    chamfer_reduce<<<NBLK2, 256, 0, stream>>>(preds, tgts, partial, blocksum, counter, out);
}